// Round 9
// baseline (48.817 us; speedup 1.0000x reference)
//
#include <hip/hip_runtime.h>
#include <hip/hip_bf16.h>

#ifndef M_PI
#define M_PI 3.14159265358979323846
#endif

// Problem constants
#define X_RANGE 256
#define Y_RANGE 256
#define NUM_ANGLES 180
#define NUM_DET 512
#define BATCH 8
#define M_ROWS (BATCH * NUM_ANGLES)      // 1440
#define AD (NUM_ANGLES * NUM_DET)        // 92160
#define NPIX (X_RANGE * Y_RANGE)         // 65536
#define MN ((size_t)M_ROWS * NUM_DET)    // 737280

typedef __attribute__((ext_vector_type(8))) short short8v;   // 8 bf16 (4 VGPRs)
typedef __attribute__((ext_vector_type(4))) float float4v;

// Load 8 consecutive f32 and convert to 8 bf16 (RNE; compiler emits v_cvt_pk_bf16_f32)
__device__ __forceinline__ short8v ldcvt8(const float* __restrict__ p) {
    const float4 lo = *reinterpret_cast<const float4*>(p);
    const float4 hi = *reinterpret_cast<const float4*>(p + 4);
    float f[8] = {lo.x, lo.y, lo.z, lo.w, hi.x, hi.y, hi.z, hi.w};
    short8v r;
#pragma unroll
    for (int j = 0; j < 8; ++j) {
        __hip_bfloat16 h = __float2bfloat16(f[j]);
        r[j] = *reinterpret_cast<short*>(&h);
    }
    return r;
}

// ---------------- Kernel 1: fused convert + bf16 MFMA filter GEMM + trig table ----------
// fil[m][e] = sum_d A[m][d] * W[e][d]  (m = b*180+a, so fil == [b][a][e]).
// 16x16x32 bf16 MFMA, f32->bf16 conversion fused into the fragment loads.
// A-frag: row=lane&15, k=8*(lane>>4)+j. B-frag: col=lane&15, same k.
// C/D: col=lane&15, row=(lane>>4)*4+reg (verified R8). Block(0,0) also writes
// the 180-entry cos/sin double table for the backprojector.
__global__ __launch_bounds__(256) void gemm_fused(const float* __restrict__ A,
                                                  const float* __restrict__ Wm,
                                                  float* __restrict__ fil,
                                                  double* __restrict__ ctab) {
    if (blockIdx.x == 0 && blockIdx.y == 0 && threadIdx.x < NUM_ANGLES) {
        const double th = (M_PI / (double)NUM_ANGLES) * (double)threadIdx.x;
        ctab[2 * threadIdx.x]     = cos(th);
        ctab[2 * threadIdx.x + 1] = sin(th);
    }

    const int w  = threadIdx.x >> 6;
    const int l  = threadIdx.x & 63;
    const int mt = blockIdx.x * 4 + w;           // m-tile, valid < 90
    const int eB = blockIdx.y * 16;
    const bool valid = (mt < 90);

    const int mRow = min(mt * 16 + (l & 15), M_ROWS - 1);
    const int kOff = (l >> 4) * 8;
    const float* ap = A  + (size_t)mRow * NUM_DET + kOff;
    const float* bp = Wm + (size_t)(eB + (l & 15)) * NUM_DET + kOff;

    float4v acc = {0.f, 0.f, 0.f, 0.f};
    short8v a0 = ldcvt8(ap);
    short8v b0 = ldcvt8(bp);

#pragma unroll
    for (int k = 0; k < 16; ++k) {
        short8v a1 = a0, b1 = b0;
        if (k < 15) {                              // prefetch+convert next K=32 chunk
            a1 = ldcvt8(ap + (k + 1) * 32);
            b1 = ldcvt8(bp + (k + 1) * 32);
        }
        acc = __builtin_amdgcn_mfma_f32_16x16x32_bf16(a0, b0, acc, 0, 0, 0);
        a0 = a1;  b0 = b1;
    }

    if (valid) {
        const int mOut = mt * 16 + (l >> 4) * 4;
        const int e = eB + (l & 15);
#pragma unroll
        for (int r = 0; r < 4; ++r)
            fil[(size_t)(mOut + r) * NUM_DET + e] = acc[r];
    }
}

// ---------------- Kernel 2: barrier-free windowed backprojection (byte-identical to R8) ----
// Block = 8x * 8y = 64-pixel tile, 256 threads = 4 waves. Wave g owns angles
// [45g, 45g+45) and a PRIVATE double-buffered 16-bin LDS window -> the whole
// angle loop runs with NO barriers (same-wave DS ops execute in issue order).
// Depth-2 prefetch hides L2 latency. Analytic coords (validated R5-R8):
// bin = rint(x'cos + y'sin) + 181, weights == 1. il provably in [1,15] -> WIN=16.
#define GANG 45
#define WIN 16

__global__ __launch_bounds__(256, 4) void backproject_win(const float* __restrict__ fil,
                                                          const double* __restrict__ ctab,
                                                          float* __restrict__ out) {
    __shared__ float4 winLo[4][2][WIN];
    __shared__ float4 winHi[4][2][WIN];
    __shared__ double angC[NUM_ANGLES], angS[NUM_ANGLES];
    __shared__ int    angE0[NUM_ANGLES];
    __shared__ float  red[3][64][9];

    const int tid  = threadIdx.x;
    const int g    = tid >> 6;
    const int lane = tid & 63;
    const int x0   = (blockIdx.x & 31) * 8;
    const int y0   = (blockIdx.x >> 5) * 8;

    if (tid < NUM_ANGLES) {
        const double c = ctab[2 * tid];
        const double s = ctab[2 * tid + 1];
        const double xl = (double)(x0 - 128), xh = (double)(x0 + 7 - 128);
        const double yl = (double)(y0 - 128), yh = (double)(y0 + 7 - 128);
        const double vmin = fmin(xl * c, xh * c) + fmin(yl * s, yh * s);
        int e0 = 181 + ((int)floor(vmin) - 1);
        e0 -= (e0 & 3);
        angC[tid] = c;  angS[tid] = s;  angE0[tid] = e0;
    }
    __syncthreads();

    const int aBase = g * GANG;
    const bool stager = (lane < 32);
    const int bS = lane >> 2, jS = lane & 3;
    const float* gsrc = fil + (size_t)bS * AD;

#define LOADW(k, dst)                                                          \
    {                                                                          \
        const int a_ = aBase + (k);                                            \
        int e_ = angE0[a_] + (jS << 2);                                        \
        e_ = min(max(e_, 0), NUM_DET - 4);                                     \
        dst = *reinterpret_cast<const float4*>(gsrc + (a_ << 9) + e_);         \
    }
#define WRITEW(k, v)                                                           \
    {                                                                          \
        float* base_ = (bS < 4) ? (float*)&winLo[g][(k) & 1][0]                \
                                : (float*)&winHi[g][(k) & 1][0];               \
        const int c_ = bS & 3;                                                 \
        const int s_ = jS << 2;                                                \
        base_[(s_ + 0) * 4 + c_] = v.x;                                        \
        base_[(s_ + 1) * 4 + c_] = v.y;                                        \
        base_[(s_ + 2) * 4 + c_] = v.z;                                        \
        base_[(s_ + 3) * 4 + c_] = v.w;                                        \
    }

    if (stager) {
        float4 v0, v1;
        LOADW(0, v0);
        LOADW(1, v1);
        WRITEW(0, v0);
        WRITEW(1, v1);
    }

    const double xd = (double)(x0 + (lane >> 3) - 128);
    const double yd = (double)(y0 + (lane & 7) - 128);

    float4 aLo = make_float4(0.f, 0.f, 0.f, 0.f);
    float4 aHi = make_float4(0.f, 0.f, 0.f, 0.f);

    for (int k = 0; k < GANG; ++k) {
        float4 stg;
        const bool doStage = stager && (k + 2 < GANG);
        if (doStage) LOADW(k + 2, stg);

        const int a = aBase + k;
        const double v = xd * angC[a] + yd * angS[a];
        int il = __double2int_rn(v) + 181 - angE0[a];
        il = min(max(il, 0), WIN - 1);
        const float4 lo = winLo[g][k & 1][il];
        const float4 hi = winHi[g][k & 1][il];
        aLo.x += lo.x;  aLo.y += lo.y;  aLo.z += lo.z;  aLo.w += lo.w;
        aHi.x += hi.x;  aHi.y += hi.y;  aHi.z += hi.z;  aHi.w += hi.w;

        if (doStage) WRITEW(k + 2, stg);
    }

    if (g > 0) {
        red[g - 1][lane][0] = aLo.x;  red[g - 1][lane][1] = aLo.y;
        red[g - 1][lane][2] = aLo.z;  red[g - 1][lane][3] = aLo.w;
        red[g - 1][lane][4] = aHi.x;  red[g - 1][lane][5] = aHi.y;
        red[g - 1][lane][6] = aHi.z;  red[g - 1][lane][7] = aHi.w;
    }
    __syncthreads();
    if (g == 0) {
        float s[8] = {aLo.x, aLo.y, aLo.z, aLo.w, aHi.x, aHi.y, aHi.z, aHi.w};
#pragma unroll
        for (int j = 0; j < 3; ++j)
#pragma unroll
            for (int b = 0; b < 8; ++b)
                s[b] += red[j][lane][b];
        const int p = (x0 + (lane >> 3)) * Y_RANGE + y0 + (lane & 7);
#pragma unroll
        for (int b = 0; b < 8; ++b)
            out[(size_t)b * NPIX + p] = s[b];
    }
#undef LOADW
#undef WRITEW
}

extern "C" void kernel_launch(void* const* d_in, const int* in_sizes, int n_in,
                              void* d_out, int out_size, void* d_ws, size_t ws_size,
                              hipStream_t stream) {
    const float* sino = (const float*)d_in[0];   // [8,1,180,512] f32
    const float* Wm   = (const float*)d_in[1];   // [512,512] f32
    float* out = (float*)d_out;                  // [8,1,256,256] f32
    float* ws  = (float*)d_ws;

    // ws layout: fil[MN] f32 | ctab[360] f64 (MN floats -> 8B aligned)
    float*  fil  = ws;
    double* ctab = (double*)(ws + MN);

    gemm_fused<<<dim3(23, 32), 256, 0, stream>>>(sino, Wm, fil, ctab);
    backproject_win<<<NPIX / 64, 256, 0, stream>>>(fil, ctab, out);
}